// Round 17
// baseline (183.557 us; speedup 1.0000x reference)
//
#include <hip/hip_runtime.h>
#include <hip/hip_bf16.h>
#include <math.h>

#define NH   4
#define DH   16
#define CH   64
#define KNN  10
#define KS   4
#define NV   4096
#define NB   4
#define MHID 256
#define BN   (NB * NV)

// canonical param-buffer offsets (f32 elements)
#define P_LN1G  0
#define P_LN1B  64
#define P_LN2G  128
#define P_LN2B  192
#define P_WQKV  256
#define P_BQKV  12544
#define P_WPROJ 12736
#define P_BPROJ 16832
#define P_W1    16896
#define P_B1    33280
#define P_W2    33536
#define P_B2    49920
#define P_TOT   49984

typedef __hip_bfloat16 bf16;
typedef __attribute__((ext_vector_type(8))) short short8;
typedef __attribute__((ext_vector_type(4))) float float4a;

__device__ __forceinline__ float b2f(bf16 x) { return __bfloat162float(x); }

__device__ __forceinline__ float cvt(const void* p, int i, int isbf) {
  return isbf ? b2f(((const bf16*)p)[i]) : ((const float*)p)[i];
}

__device__ __forceinline__ float wave_sum_f32(float v) {
#pragma unroll
  for (int m = 32; m >= 1; m >>= 1) v += __shfl_xor(v, m, 64);
  return v;
}

// lexicographic wave-min over (hi, lo) pairs (knn fallback path only)
__device__ __forceinline__ void wave_min_kv(unsigned& hi, unsigned& lo) {
#pragma unroll
  for (int m = 32; m >= 1; m >>= 1) {
    unsigned ohi = __shfl_xor(hi, m, 64);
    unsigned olo = __shfl_xor(lo, m, 64);
    if (ohi < hi || (ohi == hi && olo < lo)) { hi = ohi; lo = olo; }
  }
}

__device__ __forceinline__ float rdlane(float v, int src) {
  return __uint_as_float(__builtin_amdgcn_readlane(__float_as_uint(v), src));
}

__device__ __forceinline__ float tanh_fast(float u) {
  float e = __expf(2.0f * u);
  return 1.0f - 2.0f / (e + 1.0f);
}

// identical d2 expression everywhere (exactness anchor)
__device__ __forceinline__ float d2f(float x, float y, float z,
                                     float qx, float qy, float qz) {
  float dx = x - qx, dy = y - qy, dz = z - qz;
  return dx * dx + dy * dy + dz * dz;
}

// ---------------- K0: storage-dtype detection ----------------
__global__ __launch_bounds__(64) void k_detect(
    const unsigned short* __restrict__ x_u16,
    const unsigned* __restrict__ m_u32, int* __restrict__ flags)
{
  const int lane = threadIdx.x;
  int cnt = 0;
#pragma unroll
  for (int k = 0; k < 4; ++k) {
    unsigned short w = x_u16[lane * 4 + k];
    int e = (w >> 7) & 0xFF;
    cnt += (e >= 100 && e <= 140);
  }
#pragma unroll
  for (int m = 32; m >= 1; m >>= 1) cnt += __shfl_xor(cnt, m, 64);
  unsigned big = (m_u32[lane] > 1u) ? 1u : 0u;
#pragma unroll
  for (int m = 32; m >= 1; m >>= 1) big |= __shfl_xor(big, m, 64);
  if (lane == 0) { flags[0] = (cnt >= 205) ? 1 : 0; flags[1] = big ? 1 : 0; }
}

// ---------------- K0b: canonicalize inputs ----------------
__global__ __launch_bounds__(256) void k_ingest(
    const void* xin, const void* coords, const void* maskr,
    const void* ln1g, const void* ln1b, const void* ln2g, const void* ln2b,
    const void* wqkv, const void* bqkv, const void* wproj, const void* bproj,
    const void* w1, const void* b1, const void* w2, const void* b2,
    const int* __restrict__ flags,
    float* __restrict__ xcan, float* __restrict__ ccan,
    float* __restrict__ pcan, int* __restrict__ mcan)
{
  const int isbf = flags[0];
  const int m8 = flags[1];
  int id = blockIdx.x * 256 + threadIdx.x;
  const int n0 = BN * CH, n1 = NB * NV * 3, n2 = P_TOT, n3 = BN;
  if (id < n0) { xcan[id] = cvt(xin, id, isbf); return; }
  id -= n0;
  if (id < n1) { ccan[id] = cvt(coords, id, isbf); return; }
  id -= n1;
  if (id < n2) {
    const void* src; int off;
    if      (id < P_LN1B)  { src = ln1g;  off = id - P_LN1G; }
    else if (id < P_LN2G)  { src = ln1b;  off = id - P_LN1B; }
    else if (id < P_LN2B)  { src = ln2g;  off = id - P_LN2G; }
    else if (id < P_WQKV)  { src = ln2b;  off = id - P_LN2B; }
    else if (id < P_BQKV)  { src = wqkv;  off = id - P_WQKV; }
    else if (id < P_WPROJ) { src = bqkv;  off = id - P_BQKV; }
    else if (id < P_BPROJ) { src = wproj; off = id - P_WPROJ; }
    else if (id < P_W1)    { src = bproj; off = id - P_BPROJ; }
    else if (id < P_B1)    { src = w1;    off = id - P_W1; }
    else if (id < P_W2)    { src = b1;    off = id - P_B1; }
    else if (id < P_B2)    { src = w2;    off = id - P_W2; }
    else                   { src = b2;    off = id - P_B2; }
    pcan[id] = cvt(src, off, isbf);
    return;
  }
  id -= n2;
  if (id < n3) {
    mcan[id] = m8 ? (int)(((const unsigned char*)maskr)[id] != 0)
                  : (int)(((const int*)maskr)[id] != 0);
  }
}

// ---------------- K0d: pack w1/w2/wqkv into MFMA B-fragment order (bf16) ----------------
__global__ __launch_bounds__(256) void k_pack(
    const float* __restrict__ pcan,
    unsigned short* __restrict__ w1p, unsigned short* __restrict__ w2p,
    unsigned short* __restrict__ wqp)
{
  int id = blockIdx.x * 256 + threadIdx.x;
  if (id < 16384) {            // w1: K=64, N=256 -> nt 0..15, kh 0..1
    int j = id & 7, l = (id >> 3) & 63, kh = (id >> 9) & 1, nt = id >> 10;
    int k = kh * 32 + ((l >> 4) * 8) + j;
    int n = nt * 16 + (l & 15);
    w1p[id] = __bfloat16_as_ushort(__float2bfloat16(pcan[P_W1 + k * MHID + n]));
    return;
  }
  id -= 16384;
  if (id < 16384) {            // w2: K=256, N=64 -> nt 0..3, kh 0..7
    int j = id & 7, l = (id >> 3) & 63, kh = (id >> 9) & 7, nt = id >> 12;
    int k = kh * 32 + ((l >> 4) * 8) + j;
    int n = nt * 16 + (l & 15);
    w2p[id] = __bfloat16_as_ushort(__float2bfloat16(pcan[P_W2 + k * CH + n]));
    return;
  }
  id -= 16384;
  if (id < 12288) {            // wqkv: K=64, N=192 -> nt 0..11, kh 0..1
    int j = id & 7, l = (id >> 3) & 63, kh = (id >> 9) & 1, nt = id >> 10;
    int k = kh * 32 + ((l >> 4) * 8) + j;
    int n = nt * 16 + (l & 15);
    wqp[id] = __bfloat16_as_ushort(__float2bfloat16(pcan[P_WQKV + k * 192 + n]));
  }
}

// ---------------- K1: LN1 + QKV — MFMA version ----------------
#define XQS 72
__global__ __launch_bounds__(256) void k_ln_qkv(
    const float* __restrict__ x, const float* __restrict__ pcan,
    const unsigned short* __restrict__ wqp, float* __restrict__ qkv)
{
  __shared__ unsigned short xnb[16 * XQS];
  const int tid = threadIdx.x;
  const int wave = tid >> 6, lane = tid & 63;
  const int row0 = blockIdx.x * 16;

  {
    const float gg = pcan[P_LN1G + lane], bb = pcan[P_LN1B + lane];
#pragma unroll
    for (int r = 0; r < 4; ++r) {
      int m = wave * 4 + r;
      float v = x[(size_t)(row0 + m) * CH + lane];
      float mn = wave_sum_f32(v) * (1.0f / 64.0f);
      float d = v - mn;
      float var = wave_sum_f32(d * d) * (1.0f / 64.0f);
      float rs = 1.0f / sqrtf(var + 1e-5f);
      xnb[m * XQS + lane] =
          __bfloat16_as_ushort(__float2bfloat16(d * rs * gg + bb));
    }
  }
  __syncthreads();

  const int q = lane >> 4, c = lane & 15;
  short8 a0 = *(const short8*)&xnb[c * XQS + q * 8];
  short8 a1 = *(const short8*)&xnb[c * XQS + 32 + q * 8];

#pragma unroll
  for (int t = 0; t < 3; ++t) {
    int nt = wave * 3 + t;
    short8 b0 = *(const short8*)&wqp[(size_t)((nt * 2 + 0) * 64 + lane) * 8];
    short8 b1 = *(const short8*)&wqp[(size_t)((nt * 2 + 1) * 64 + lane) * 8];
    float4a z = {0.f, 0.f, 0.f, 0.f};
    z = __builtin_amdgcn_mfma_f32_16x16x32_bf16(a0, b0, z, 0, 0, 0);
    z = __builtin_amdgcn_mfma_f32_16x16x32_bf16(a1, b1, z, 0, 0, 0);
    int n = nt * 16 + c;
    float bq = pcan[P_BQKV + n];
#pragma unroll
    for (int r = 0; r < 4; ++r) {
      int m = q * 4 + r;
      qkv[(size_t)(row0 + m) * 192 + n] = z[r] + bq;
    }
  }
}

// ---------------- K2: KNN — chunked, register-resident d2 for chunk0 ----------------
// Chunk0: d2 -> regs (32/lane), min -> T (subset 10th >= global 10th),
// compact from regs (no LDS re-read, no recompute). Chunk1: fused
// compute+compact. Exact (d2bits,j) rank = jax tie-break; fallback intact.
#define KROWS 4
#define CAP   128
#define HALF  2048
__global__ __launch_bounds__(256) void k_knn(
    const float* __restrict__ ccan, const int* __restrict__ mcan,
    int* __restrict__ nbr)
{
  __shared__ float4 sx[HALF / 4], sy[HALF / 4], sz[HALF / 4];   // 24 KB SoA
  __shared__ unsigned long long sbuf[KROWS][CAP];               // 4 KB
  const int tid = threadIdx.x;
  const int row0 = blockIdx.x * KROWS;
  const int b = row0 >> 12;
  const float* cb = ccan + (size_t)b * NV * 3;
  const int* mb = mcan + b * NV;
  float* fx = (float*)sx; float* fy = (float*)sy; float* fz = (float*)sz;

  // stage chunk0 (j in [0, 2048)), mask folded (invalid -> 1e4 => d2 ~3e8)
  for (int j = tid; j < HALF; j += 256) {
    bool v = mb[j] != 0;
    fx[j] = v ? cb[j * 3] : 1e4f;
    fy[j] = v ? cb[j * 3 + 1] : 1e4f;
    fz[j] = v ? cb[j * 3 + 2] : 1e4f;
  }
  __syncthreads();
  const int wave = tid >> 6, lane = tid & 63;
  const int qi = (row0 & (NV - 1)) + wave;
  const float qx = cb[qi * 3], qy = cb[qi * 3 + 1], qz = cb[qi * 3 + 2];
  const int grow = row0 + wave;
  const unsigned long long below = (lane == 0) ? 0ull : (~0ull >> (64 - lane));

  // ---- chunk0: d2 into registers + per-lane min ----
  float dsq[32];
  float bmin = 1e30f;
#pragma unroll
  for (int t = 0; t < 8; ++t) {
    float4 X = sx[lane + t * 64], Y = sy[lane + t * 64], Z = sz[lane + t * 64];
    dsq[t * 4 + 0] = d2f(X.x, Y.x, Z.x, qx, qy, qz);
    dsq[t * 4 + 1] = d2f(X.y, Y.y, Z.y, qx, qy, qz);
    dsq[t * 4 + 2] = d2f(X.z, Y.z, Z.z, qx, qy, qz);
    dsq[t * 4 + 3] = d2f(X.w, Y.w, Z.w, qx, qy, qz);
    bmin = fminf(bmin, fminf(fminf(dsq[t * 4], dsq[t * 4 + 1]),
                             fminf(dsq[t * 4 + 2], dsq[t * 4 + 3])));
  }
  const unsigned lm = __float_as_uint(bmin);
  unsigned acc = 0;
#pragma unroll 1
  for (int bit = 31; bit >= 0; --bit) {
    unsigned tr = acc | (1u << bit);
    int cnt = __popcll(__ballot(lm < tr));
    if (cnt <= KNN - 1) acc = tr;
  }
  const float T = __uint_as_float(acc + 8);

  // ---- compact chunk0 survivors from registers ----
  int base = 0;
#pragma unroll
  for (int t = 0; t < 8; ++t) {
#pragma unroll
    for (int e = 0; e < 4; ++e) {
      float d2 = dsq[t * 4 + e];
      bool s = (d2 <= T);
      unsigned long long bal = __ballot(s);
      if (bal) {
        int pos = base + __popcll(bal & below);
        unsigned j = 4u * (unsigned)(lane + t * 64) + (unsigned)e;
        if (s && pos < CAP)
          sbuf[wave][pos] =
              ((unsigned long long)__float_as_uint(d2) << 32) | j;
        base += __popcll(bal);
      }
    }
  }
  __syncthreads();   // all waves done reading chunk0

  // stage chunk1 (j in [2048, 4096)) into the same buffers
  for (int j = tid; j < HALF; j += 256) {
    int jj = j + HALF;
    bool v = mb[jj] != 0;
    fx[j] = v ? cb[jj * 3] : 1e4f;
    fy[j] = v ? cb[jj * 3 + 1] : 1e4f;
    fz[j] = v ? cb[jj * 3 + 2] : 1e4f;
  }
  __syncthreads();

  // ---- chunk1: fused compute + compact ----
#pragma unroll 4
  for (int t = 0; t < 8; ++t) {
    float4 X = sx[lane + t * 64], Y = sy[lane + t * 64], Z = sz[lane + t * 64];
    float dd[4];
    dd[0] = d2f(X.x, Y.x, Z.x, qx, qy, qz);
    dd[1] = d2f(X.y, Y.y, Z.y, qx, qy, qz);
    dd[2] = d2f(X.z, Y.z, Z.z, qx, qy, qz);
    dd[3] = d2f(X.w, Y.w, Z.w, qx, qy, qz);
#pragma unroll
    for (int e = 0; e < 4; ++e) {
      bool s = (dd[e] <= T);
      unsigned long long bal = __ballot(s);
      if (bal) {
        int pos = base + __popcll(bal & below);
        unsigned j = (unsigned)HALF + 4u * (unsigned)(lane + t * 64) + (unsigned)e;
        if (s && pos < CAP)
          sbuf[wave][pos] =
              ((unsigned long long)__float_as_uint(dd[e]) << 32) | j;
        base += __popcll(bal);
      }
    }
  }
  const int c = base;

  if (c >= KNN && c <= CAP) {
    // exact rank-by-count on (d2bits, j) keys == jax tie-break
#pragma unroll
    for (int o = 0; o < 2; ++o) {
      int idx = lane + o * 64;
      if (idx < c) {
        unsigned long long mykey = sbuf[wave][idx];
        int rank = 0;
        for (int i = 0; i < c; ++i) rank += (sbuf[wave][i] < mykey);
        if (rank < KNN)
          nbr[(size_t)grow * KNN + rank] = (int)(mykey & (NV - 1));
      }
    }
  } else {
    // exact brute force from GLOBAL (jax semantics: invalid -> d2=1e9)
    unsigned long long arr[KNN];
#pragma unroll
    for (int t = 0; t < KNN; ++t) arr[t] = ~0ull;
    for (int j = lane; j < NV; j += 64) {
      float d2 = d2f(cb[j * 3], cb[j * 3 + 1], cb[j * 3 + 2], qx, qy, qz);
      if (!mb[j]) d2 = 1e9f;
      unsigned long long key =
          ((unsigned long long)__float_as_uint(d2) << 32) | (unsigned)j;
      if (key < arr[KNN - 1]) {
        arr[KNN - 1] = key;
#pragma unroll
        for (int t2 = KNN - 1; t2 > 0; --t2) {
          unsigned long long a = arr[t2 - 1], cc2 = arr[t2];
          if (cc2 < a) { arr[t2 - 1] = cc2; arr[t2] = a; }
        }
      }
    }
    unsigned myj = 0;
#pragma unroll 1
    for (int r = 0; r < KNN; ++r) {
      unsigned hi = (unsigned)(arr[0] >> 32);
      unsigned lo = (unsigned)(arr[0] & 0xffffffffu);
      unsigned ohi = hi, olo = lo;
      wave_min_kv(hi, lo);
      if (ohi == hi && olo == lo) {   // unique keys: owner lane pops
#pragma unroll
        for (int t = 0; t < KNN - 1; ++t) arr[t] = arr[t + 1];
        arr[KNN - 1] = ~0ull;
      }
      if (lane == r) myj = lo;
    }
    if (lane < KNN)
      nbr[(size_t)grow * KNN + lane] = (int)(myj & (NV - 1));
  }
}

// ---------------- K3: attention + proj + residual (R9 version) ----------------
#define AROWS 4
__global__ __launch_bounds__(256) void k_attn(
    const float* __restrict__ qkv, const int* __restrict__ nbr,
    const int* __restrict__ mcan, const float* __restrict__ xcan,
    const float* __restrict__ pcan, float* __restrict__ xres)
{
  __shared__ float wp[CH * CH];
  __shared__ float bp[CH];
  __shared__ float sc[AROWS][NH][KNN];
  __shared__ float wsel[AROWS][NH][KS];
  __shared__ int   isel[AROWS][NH][KS];
  __shared__ float obuf[AROWS][CH];
  __shared__ int   nb[AROWS][KNN];
  __shared__ float npen[AROWS][KNN];
  const int tid = threadIdx.x;
  {
    const float4* src = (const float4*)(pcan + P_WPROJ);
    float4* dst = (float4*)wp;
    for (int i = tid; i < CH * CH / 4; i += 256) dst[i] = src[i];
    if (tid < CH) bp[tid] = pcan[P_BPROJ + tid];
  }
  const int wave = tid >> 6, lane = tid & 63;
  const int row = blockIdx.x * AROWS + wave;
  const int b = row / NV;

  if (lane < KNN) {
    int j = nbr[(size_t)row * KNN + lane] & (NV - 1);
    nb[wave][lane] = j;
    npen[wave][lane] = mcan[b * NV + j] ? 0.0f : -1e9f;
  }
  __syncthreads();

  if (lane < NH * KNN) {
    int h = lane / KNN, kk = lane % KNN;
    int j = nb[wave][kk];
    const float* qp = qkv + (size_t)row * 192 + h * DH;
    const float* kp = qkv + ((size_t)(b * NV + j)) * 192 + 64 + h * DH;
    float acc = 0.f;
#pragma unroll
    for (int d = 0; d < DH; ++d) acc += qp[d] * kp[d];
    sc[wave][h][kk] = acc * 0.25f + npen[wave][kk];
  }
  __syncthreads();

  if (lane < NH) {
    int h = lane;
    float sv[KS]; int sj[KS];
    unsigned used = 0;
#pragma unroll
    for (int r = 0; r < KS; ++r) {
      float best = -INFINITY; int bi = 0;
#pragma unroll
      for (int kk = 0; kk < KNN; ++kk) {
        float s = sc[wave][h][kk];
        if (!(used & (1u << kk)) && s > best) { best = s; bi = kk; }
      }
      used |= 1u << bi; sv[r] = best; sj[r] = bi;
    }
    float mx = sv[0];
    float e[KS], sum = 0.f;
#pragma unroll
    for (int r = 0; r < KS; ++r) { e[r] = expf(sv[r] - mx); sum += e[r]; }
    float inv = 1.0f / sum;
#pragma unroll
    for (int r = 0; r < KS; ++r) {
      wsel[wave][h][r] = e[r] * inv;
      isel[wave][h][r] = nb[wave][sj[r]];
    }
  }
  __syncthreads();

  {
    int h = lane >> 4, d = lane & 15;
    float o = 0.f;
#pragma unroll
    for (int r = 0; r < KS; ++r) {
      int j = isel[wave][h][r];
      o += wsel[wave][h][r] * qkv[((size_t)(b * NV + j)) * 192 + 128 + h * DH + d];
    }
    obuf[wave][lane] = o;
  }
  __syncthreads();

  {
    float acc = bp[lane];
#pragma unroll 4
    for (int cc = 0; cc < CH; ++cc)
      acc = fmaf(obuf[wave][cc], wp[cc * CH + lane], acc);
    float a = mcan[row] ? acc : 0.0f;
    xres[(size_t)row * CH + lane] = 0.5f * a + xcan[(size_t)row * CH + lane];
  }
}

// ---------------- K4: LN2 + MLP + residual — MFMA version (R13) ----------------
#define XNS 72
#define GS  264
__global__ __launch_bounds__(256) void k_mlp(
    const float* __restrict__ xres, const float* __restrict__ pcan,
    const unsigned short* __restrict__ w1p,
    const unsigned short* __restrict__ w2p,
    const int* __restrict__ flags, void* __restrict__ out)
{
  __shared__ unsigned short xnb[16 * XNS];
  __shared__ unsigned short gb[16 * GS];
  const int tid = threadIdx.x;
  const int wave = tid >> 6, lane = tid & 63;
  const int row0 = blockIdx.x * 16;

  {
    const float gg = pcan[P_LN2G + lane], bb2 = pcan[P_LN2B + lane];
#pragma unroll
    for (int r = 0; r < 4; ++r) {
      int m = wave * 4 + r;
      float v = xres[(size_t)(row0 + m) * CH + lane];
      float mn = wave_sum_f32(v) * (1.0f / 64.0f);
      float d = v - mn;
      float var = wave_sum_f32(d * d) * (1.0f / 64.0f);
      float rs = 1.0f / sqrtf(var + 1e-5f);
      xnb[m * XNS + lane] =
          __bfloat16_as_ushort(__float2bfloat16(d * rs * gg + bb2));
    }
  }
  __syncthreads();

  const int q = lane >> 4, c = lane & 15;
  short8 a0 = *(const short8*)&xnb[c * XNS + q * 8];
  short8 a1 = *(const short8*)&xnb[c * XNS + 32 + q * 8];

  // ---- fc1 ----
  float4a acc[4];
#pragma unroll
  for (int t = 0; t < 4; ++t) {
    int nt = wave * 4 + t;
    short8 b0 = *(const short8*)&w1p[(size_t)((nt * 2 + 0) * 64 + lane) * 8];
    short8 b1 = *(const short8*)&w1p[(size_t)((nt * 2 + 1) * 64 + lane) * 8];
    float4a z = {0.f, 0.f, 0.f, 0.f};
    z = __builtin_amdgcn_mfma_f32_16x16x32_bf16(a0, b0, z, 0, 0, 0);
    z = __builtin_amdgcn_mfma_f32_16x16x32_bf16(a1, b1, z, 0, 0, 0);
    acc[t] = z;
  }
#pragma unroll
  for (int t = 0; t < 4; ++t) {
    int n = (wave * 4 + t) * 16 + c;
    float bo = pcan[P_B1 + n];
#pragma unroll
    for (int r = 0; r < 4; ++r) {
      float h = acc[t][r] + bo;
      float u = 0.7978845608028654f * (h + 0.044715f * h * h * h);
      float gv = 0.5f * h * (1.0f + tanh_fast(u));
      gb[(q * 4 + r) * GS + n] = __bfloat16_as_ushort(__float2bfloat16(gv));
    }
  }
  __syncthreads();

  // ---- fc2 ----
  float4a o = {0.f, 0.f, 0.f, 0.f};
#pragma unroll
  for (int kh = 0; kh < 8; ++kh) {
    short8 ag = *(const short8*)&gb[c * GS + kh * 32 + q * 8];
    short8 bg = *(const short8*)&w2p[(size_t)((wave * 8 + kh) * 64 + lane) * 8];
    o = __builtin_amdgcn_mfma_f32_16x16x32_bf16(ag, bg, o, 0, 0, 0);
  }
  {
    int n = wave * 16 + c;
    float b2v = pcan[P_B2 + n];
    const int isbf = flags[0];
#pragma unroll
    for (int r = 0; r < 4; ++r) {
      int m = q * 4 + r;
      size_t idx = (size_t)(row0 + m) * CH + n;
      float val = 0.5f * (o[r] + b2v) + xres[idx];
      if (isbf) ((bf16*)out)[idx] = __float2bfloat16(val);
      else      ((float*)out)[idx] = val;
    }
  }
}

extern "C" void kernel_launch(void* const* d_in, const int* in_sizes, int n_in,
                              void* d_out, int out_size, void* d_ws, size_t ws_size,
                              hipStream_t stream)
{
  char* ws = (char*)d_ws;
  float* qkv   = (float*)(ws);
  float* xres  = (float*)(ws + 12582912);
  float* xcan  = (float*)(ws + 16777216);
  float* ccan  = (float*)(ws + 20971520);
  float* pcan  = (float*)(ws + 21168128);
  int*   mcan  = (int*)  (ws + 21368064);
  int*   nbr   = (int*)  (ws + 21433600);
  int*   flags = (int*)  (ws + 22088960);
  unsigned short* w1p = (unsigned short*)(ws + 22089728);   // 32 KB
  unsigned short* w2p = (unsigned short*)(ws + 22122496);   // 32 KB
  unsigned short* wqp = (unsigned short*)(ws + 22155264);   // 24 KB

  k_detect<<<1, 64, 0, stream>>>((const unsigned short*)d_in[0],
                                 (const unsigned*)d_in[2], flags);
  const int total = BN * CH + NB * NV * 3 + P_TOT + BN;
  k_ingest<<<(total + 255) / 256, 256, 0, stream>>>(
      d_in[0], d_in[1], d_in[2], d_in[3], d_in[4], d_in[5], d_in[6],
      d_in[7], d_in[8], d_in[9], d_in[10], d_in[11], d_in[12], d_in[13], d_in[14],
      flags, xcan, ccan, pcan, mcan);
  k_pack<<<176, 256, 0, stream>>>(pcan, w1p, w2p, wqp);
  k_ln_qkv<<<BN / 16, 256, 0, stream>>>(xcan, pcan, wqp, qkv);
  k_knn<<<BN / KROWS, 256, 0, stream>>>(ccan, mcan, nbr);
  k_attn<<<BN / AROWS, 256, 0, stream>>>(qkv, nbr, mcan, xcan, pcan, xres);
  k_mlp<<<BN / 16, 256, 0, stream>>>(xres, pcan, w1p, w2p, flags, d_out);
}

// Round 18
// 174.534 us; speedup vs baseline: 1.0517x; 1.0517x over previous
//
#include <hip/hip_runtime.h>
#include <hip/hip_bf16.h>
#include <math.h>

#define NH   4
#define DH   16
#define CH   64
#define KNN  10
#define KS   4
#define NV   4096
#define NB   4
#define MHID 256
#define BN   (NB * NV)

// canonical param-buffer offsets (f32 elements)
#define P_LN1G  0
#define P_LN1B  64
#define P_LN2G  128
#define P_LN2B  192
#define P_WQKV  256
#define P_BQKV  12544
#define P_WPROJ 12736
#define P_BPROJ 16832
#define P_W1    16896
#define P_B1    33280
#define P_W2    33536
#define P_B2    49920
#define P_TOT   49984

#define N_ING  (BN * CH + NB * NV * 3 + P_TOT + BN)   // 1,164,096
#define N_PACK (16384 + 16384 + 12288)                // 45,056

typedef __hip_bfloat16 bf16;
typedef __attribute__((ext_vector_type(8))) short short8;
typedef __attribute__((ext_vector_type(4))) float float4a;

__device__ __forceinline__ float b2f(bf16 x) { return __bfloat162float(x); }

__device__ __forceinline__ float cvt(const void* p, int i, int isbf) {
  return isbf ? b2f(((const bf16*)p)[i]) : ((const float*)p)[i];
}

__device__ __forceinline__ float wave_sum_f32(float v) {
#pragma unroll
  for (int m = 32; m >= 1; m >>= 1) v += __shfl_xor(v, m, 64);
  return v;
}

// lexicographic wave-min over (hi, lo) pairs (knn fallback path only)
__device__ __forceinline__ void wave_min_kv(unsigned& hi, unsigned& lo) {
#pragma unroll
  for (int m = 32; m >= 1; m >>= 1) {
    unsigned ohi = __shfl_xor(hi, m, 64);
    unsigned olo = __shfl_xor(lo, m, 64);
    if (ohi < hi || (ohi == hi && olo < lo)) { hi = ohi; lo = olo; }
  }
}

__device__ __forceinline__ float tanh_fast(float u) {
  float e = __expf(2.0f * u);
  return 1.0f - 2.0f / (e + 1.0f);
}

// identical d2 expression everywhere (exactness anchor)
__device__ __forceinline__ float d2f(float x, float y, float z,
                                     float qx, float qy, float qz) {
  float dx = x - qx, dy = y - qy, dz = z - qz;
  return dx * dx + dy * dy + dz * dz;
}

// ---------------- K0: fused detect + ingest + pack ----------------
// Every block recomputes the storage-dtype flags locally (256 L2-hot u16
// reads + ballots) -- no 1-block detect kernel, no separate pack launch.
__global__ __launch_bounds__(256) void k_prep(
    const void* xin, const void* coords, const void* maskr,
    const void* ln1g, const void* ln1b, const void* ln2g, const void* ln2b,
    const void* wqkv, const void* bqkv, const void* wproj, const void* bproj,
    const void* w1, const void* b1, const void* w2, const void* b2,
    float* __restrict__ xcan, float* __restrict__ ccan,
    float* __restrict__ pcan, int* __restrict__ mcan,
    unsigned short* __restrict__ w1p, unsigned short* __restrict__ w2p,
    unsigned short* __restrict__ wqp, int* __restrict__ flags)
{
  __shared__ int sfl[2];
  const int tid = threadIdx.x;
  if (tid < 64) {
    const unsigned short* xu = (const unsigned short*)xin;
    const unsigned* mu = (const unsigned*)maskr;
    int cnt = 0;
#pragma unroll
    for (int k = 0; k < 4; ++k) {
      unsigned short w = xu[tid * 4 + k];
      int e = (w >> 7) & 0xFF;
      cnt += (e >= 100 && e <= 140);
    }
#pragma unroll
    for (int m = 32; m >= 1; m >>= 1) cnt += __shfl_xor(cnt, m, 64);
    unsigned big = (mu[tid] > 1u) ? 1u : 0u;
#pragma unroll
    for (int m = 32; m >= 1; m >>= 1) big |= __shfl_xor(big, m, 64);
    if (tid == 0) {
      sfl[0] = (cnt >= 205) ? 1 : 0;
      sfl[1] = big ? 1 : 0;
      if (blockIdx.x == 0) { flags[0] = sfl[0]; flags[1] = sfl[1]; }
    }
  }
  __syncthreads();
  const int isbf = sfl[0], m8 = sfl[1];

  int id = blockIdx.x * 256 + tid;
  const int n0 = BN * CH, n1 = NB * NV * 3, n2 = P_TOT, n3 = BN;
  if (id < n0) { xcan[id] = cvt(xin, id, isbf); return; }
  id -= n0;
  if (id < n1) { ccan[id] = cvt(coords, id, isbf); return; }
  id -= n1;
  if (id < n2) {
    const void* src; int off;
    if      (id < P_LN1B)  { src = ln1g;  off = id - P_LN1G; }
    else if (id < P_LN2G)  { src = ln1b;  off = id - P_LN1B; }
    else if (id < P_LN2B)  { src = ln2g;  off = id - P_LN2G; }
    else if (id < P_WQKV)  { src = ln2b;  off = id - P_LN2B; }
    else if (id < P_BQKV)  { src = wqkv;  off = id - P_WQKV; }
    else if (id < P_WPROJ) { src = bqkv;  off = id - P_BQKV; }
    else if (id < P_BPROJ) { src = wproj; off = id - P_WPROJ; }
    else if (id < P_W1)    { src = bproj; off = id - P_BPROJ; }
    else if (id < P_B1)    { src = w1;    off = id - P_W1; }
    else if (id < P_W2)    { src = b1;    off = id - P_B1; }
    else if (id < P_B2)    { src = w2;    off = id - P_W2; }
    else                   { src = b2;    off = id - P_B2; }
    pcan[id] = cvt(src, off, isbf);
    return;
  }
  id -= n2;
  if (id < n3) {
    mcan[id] = m8 ? (int)(((const unsigned char*)maskr)[id] != 0)
                  : (int)(((const int*)maskr)[id] != 0);
    return;
  }
  id -= n3;
  // ---- pack (reads RAW weight inputs; B-frag layout for 16x16x32) ----
  if (id < 16384) {            // w1: K=64, N=256 -> nt 0..15, kh 0..1
    int j = id & 7, l = (id >> 3) & 63, kh = (id >> 9) & 1, nt = id >> 10;
    int k = kh * 32 + ((l >> 4) * 8) + j;
    int n = nt * 16 + (l & 15);
    w1p[id] = __bfloat16_as_ushort(__float2bfloat16(cvt(w1, k * MHID + n, isbf)));
    return;
  }
  id -= 16384;
  if (id < 16384) {            // w2: K=256, N=64 -> nt 0..3, kh 0..7
    int j = id & 7, l = (id >> 3) & 63, kh = (id >> 9) & 7, nt = id >> 12;
    int k = kh * 32 + ((l >> 4) * 8) + j;
    int n = nt * 16 + (l & 15);
    w2p[id] = __bfloat16_as_ushort(__float2bfloat16(cvt(w2, k * CH + n, isbf)));
    return;
  }
  id -= 16384;
  if (id < 12288) {            // wqkv: K=64, N=192 -> nt 0..11, kh 0..1
    int j = id & 7, l = (id >> 3) & 63, kh = (id >> 9) & 1, nt = id >> 10;
    int k = kh * 32 + ((l >> 4) * 8) + j;
    int n = nt * 16 + (l & 15);
    wqp[id] = __bfloat16_as_ushort(__float2bfloat16(cvt(wqkv, k * 192 + n, isbf)));
  }
}

// ---------------- K1: LN1 + QKV — MFMA version ----------------
#define XQS 72
__global__ __launch_bounds__(256) void k_ln_qkv(
    const float* __restrict__ x, const float* __restrict__ pcan,
    const unsigned short* __restrict__ wqp, float* __restrict__ qkv)
{
  __shared__ unsigned short xnb[16 * XQS];
  const int tid = threadIdx.x;
  const int wave = tid >> 6, lane = tid & 63;
  const int row0 = blockIdx.x * 16;

  {
    const float gg = pcan[P_LN1G + lane], bb = pcan[P_LN1B + lane];
#pragma unroll
    for (int r = 0; r < 4; ++r) {
      int m = wave * 4 + r;
      float v = x[(size_t)(row0 + m) * CH + lane];
      float mn = wave_sum_f32(v) * (1.0f / 64.0f);
      float d = v - mn;
      float var = wave_sum_f32(d * d) * (1.0f / 64.0f);
      float rs = 1.0f / sqrtf(var + 1e-5f);
      xnb[m * XQS + lane] =
          __bfloat16_as_ushort(__float2bfloat16(d * rs * gg + bb));
    }
  }
  __syncthreads();

  const int q = lane >> 4, c = lane & 15;
  short8 a0 = *(const short8*)&xnb[c * XQS + q * 8];
  short8 a1 = *(const short8*)&xnb[c * XQS + 32 + q * 8];

#pragma unroll
  for (int t = 0; t < 3; ++t) {
    int nt = wave * 3 + t;
    short8 b0 = *(const short8*)&wqp[(size_t)((nt * 2 + 0) * 64 + lane) * 8];
    short8 b1 = *(const short8*)&wqp[(size_t)((nt * 2 + 1) * 64 + lane) * 8];
    float4a z = {0.f, 0.f, 0.f, 0.f};
    z = __builtin_amdgcn_mfma_f32_16x16x32_bf16(a0, b0, z, 0, 0, 0);
    z = __builtin_amdgcn_mfma_f32_16x16x32_bf16(a1, b1, z, 0, 0, 0);
    int n = nt * 16 + c;
    float bq = pcan[P_BQKV + n];
#pragma unroll
    for (int r = 0; r < 4; ++r) {
      int m = q * 4 + r;
      qkv[(size_t)(row0 + m) * 192 + n] = z[r] + bq;
    }
  }
}

// ---------------- K2: KNN — exact R14 champion (58.2 us) ----------------
#define KROWS 4
#define CAP   128
__global__ __launch_bounds__(256) void k_knn(
    const float* __restrict__ ccan, const int* __restrict__ mcan,
    int* __restrict__ nbr)
{
  __shared__ float4 sx[NV / 4], sy[NV / 4], sz[NV / 4];   // 48 KB SoA
  __shared__ unsigned long long sbuf[KROWS][CAP];         // 4 KB
  const int tid = threadIdx.x;
  const int row0 = blockIdx.x * KROWS;
  const int b = row0 >> 12;
  const float* cb = ccan + (size_t)b * NV * 3;
  const int* mb = mcan + b * NV;

  float* fx = (float*)sx; float* fy = (float*)sy; float* fz = (float*)sz;
  for (int j = tid; j < NV; j += 256) {
    bool v = mb[j] != 0;
    float x = cb[j * 3], y = cb[j * 3 + 1], z = cb[j * 3 + 2];
    fx[j] = v ? x : 1e4f;
    fy[j] = v ? y : 1e4f;
    fz[j] = v ? z : 1e4f;
  }
  __syncthreads();
  const int wave = tid >> 6, lane = tid & 63;
  const int qi = (row0 & (NV - 1)) + wave;
  const float qx = cb[qi * 3], qy = cb[qi * 3 + 1], qz = cb[qi * 3 + 2];

  float bmin = 1e30f;
#pragma unroll 4
  for (int t = 0; t < 16; ++t) {
    float4 X = sx[lane + t * 64], Y = sy[lane + t * 64], Z = sz[lane + t * 64];
    float d0 = d2f(X.x, Y.x, Z.x, qx, qy, qz);
    float d1 = d2f(X.y, Y.y, Z.y, qx, qy, qz);
    float d2 = d2f(X.z, Y.z, Z.z, qx, qy, qz);
    float d3 = d2f(X.w, Y.w, Z.w, qx, qy, qz);
    bmin = fminf(bmin, fminf(fminf(d0, d1), fminf(d2, d3)));
  }

  const unsigned lm = __float_as_uint(bmin);
  unsigned acc = 0;
#pragma unroll 1
  for (int bit = 31; bit >= 0; --bit) {
    unsigned tr = acc | (1u << bit);
    int cnt = __popcll(__ballot(lm < tr));
    if (cnt <= KNN - 1) acc = tr;
  }
  const float T = __uint_as_float(acc + 8);

  int base = 0;
  const unsigned long long below = (lane == 0) ? 0ull : (~0ull >> (64 - lane));
#pragma unroll 4
  for (int t = 0; t < 16; ++t) {
    float4 X = sx[lane + t * 64], Y = sy[lane + t * 64], Z = sz[lane + t * 64];
    float dd[4];
    dd[0] = d2f(X.x, Y.x, Z.x, qx, qy, qz);
    dd[1] = d2f(X.y, Y.y, Z.y, qx, qy, qz);
    dd[2] = d2f(X.z, Y.z, Z.z, qx, qy, qz);
    dd[3] = d2f(X.w, Y.w, Z.w, qx, qy, qz);
#pragma unroll
    for (int e = 0; e < 4; ++e) {
      bool s = (dd[e] <= T);
      unsigned long long bal = __ballot(s);
      if (bal) {
        int pos = base + __popcll(bal & below);
        unsigned j = 4u * (unsigned)(lane + t * 64) + (unsigned)e;
        if (s && pos < CAP)
          sbuf[wave][pos] =
              ((unsigned long long)__float_as_uint(dd[e]) << 32) | j;
        base += __popcll(bal);
      }
    }
  }
  const int c = base;
  const int grow = row0 + wave;

  if (c >= KNN && c <= CAP) {
#pragma unroll
    for (int o = 0; o < 2; ++o) {
      int idx = lane + o * 64;
      if (idx < c) {
        unsigned long long mykey = sbuf[wave][idx];
        int rank = 0;
        for (int i = 0; i < c; ++i) rank += (sbuf[wave][i] < mykey);
        if (rank < KNN)
          nbr[(size_t)grow * KNN + rank] = (int)(mykey & (NV - 1));
      }
    }
  } else {
    unsigned long long arr[KNN];
#pragma unroll
    for (int t = 0; t < KNN; ++t) arr[t] = ~0ull;
    for (int t = 0; t < 16; ++t) {
      float4 X = sx[lane + t * 64], Y = sy[lane + t * 64], Z = sz[lane + t * 64];
      float dd[4];
      dd[0] = d2f(X.x, Y.x, Z.x, qx, qy, qz);
      dd[1] = d2f(X.y, Y.y, Z.y, qx, qy, qz);
      dd[2] = d2f(X.z, Y.z, Z.z, qx, qy, qz);
      dd[3] = d2f(X.w, Y.w, Z.w, qx, qy, qz);
#pragma unroll
      for (int e = 0; e < 4; ++e) {
        unsigned j = 4u * (unsigned)(lane + t * 64) + (unsigned)e;
        unsigned long long key =
            ((unsigned long long)__float_as_uint(dd[e]) << 32) | j;
        if (key < arr[KNN - 1]) {
          arr[KNN - 1] = key;
#pragma unroll
          for (int t2 = KNN - 1; t2 > 0; --t2) {
            unsigned long long a = arr[t2 - 1], cc = arr[t2];
            if (cc < a) { arr[t2 - 1] = cc; arr[t2] = a; }
          }
        }
      }
    }
    unsigned myj = 0;
#pragma unroll 1
    for (int r = 0; r < KNN; ++r) {
      unsigned hi = (unsigned)(arr[0] >> 32);
      unsigned lo = (unsigned)(arr[0] & 0xffffffffu);
      wave_min_kv(hi, lo);
      if (lane == (int)((lo >> 2) & 63u)) {
#pragma unroll
        for (int t = 0; t < KNN - 1; ++t) arr[t] = arr[t + 1];
        arr[KNN - 1] = ~0ull;
      }
      if (lane == r) myj = lo;
    }
    if (lane < KNN) nbr[(size_t)grow * KNN + lane] = (int)(myj & (NV - 1));
  }
}

// ---------------- K3: attention + proj + residual (R9 version) ----------------
#define AROWS 4
__global__ __launch_bounds__(256) void k_attn(
    const float* __restrict__ qkv, const int* __restrict__ nbr,
    const int* __restrict__ mcan, const float* __restrict__ xcan,
    const float* __restrict__ pcan, float* __restrict__ xres)
{
  __shared__ float wp[CH * CH];
  __shared__ float bp[CH];
  __shared__ float sc[AROWS][NH][KNN];
  __shared__ float wsel[AROWS][NH][KS];
  __shared__ int   isel[AROWS][NH][KS];
  __shared__ float obuf[AROWS][CH];
  __shared__ int   nb[AROWS][KNN];
  __shared__ float npen[AROWS][KNN];
  const int tid = threadIdx.x;
  {
    const float4* src = (const float4*)(pcan + P_WPROJ);
    float4* dst = (float4*)wp;
    for (int i = tid; i < CH * CH / 4; i += 256) dst[i] = src[i];
    if (tid < CH) bp[tid] = pcan[P_BPROJ + tid];
  }
  const int wave = tid >> 6, lane = tid & 63;
  const int row = blockIdx.x * AROWS + wave;
  const int b = row / NV;

  if (lane < KNN) {
    int j = nbr[(size_t)row * KNN + lane] & (NV - 1);
    nb[wave][lane] = j;
    npen[wave][lane] = mcan[b * NV + j] ? 0.0f : -1e9f;
  }
  __syncthreads();

  if (lane < NH * KNN) {
    int h = lane / KNN, kk = lane % KNN;
    int j = nb[wave][kk];
    const float* qp = qkv + (size_t)row * 192 + h * DH;
    const float* kp = qkv + ((size_t)(b * NV + j)) * 192 + 64 + h * DH;
    float acc = 0.f;
#pragma unroll
    for (int d = 0; d < DH; ++d) acc += qp[d] * kp[d];
    sc[wave][h][kk] = acc * 0.25f + npen[wave][kk];
  }
  __syncthreads();

  if (lane < NH) {
    int h = lane;
    float sv[KS]; int sj[KS];
    unsigned used = 0;
#pragma unroll
    for (int r = 0; r < KS; ++r) {
      float best = -INFINITY; int bi = 0;
#pragma unroll
      for (int kk = 0; kk < KNN; ++kk) {
        float s = sc[wave][h][kk];
        if (!(used & (1u << kk)) && s > best) { best = s; bi = kk; }
      }
      used |= 1u << bi; sv[r] = best; sj[r] = bi;
    }
    float mx = sv[0];
    float e[KS], sum = 0.f;
#pragma unroll
    for (int r = 0; r < KS; ++r) { e[r] = expf(sv[r] - mx); sum += e[r]; }
    float inv = 1.0f / sum;
#pragma unroll
    for (int r = 0; r < KS; ++r) {
      wsel[wave][h][r] = e[r] * inv;
      isel[wave][h][r] = nb[wave][sj[r]];
    }
  }
  __syncthreads();

  {
    int h = lane >> 4, d = lane & 15;
    float o = 0.f;
#pragma unroll
    for (int r = 0; r < KS; ++r) {
      int j = isel[wave][h][r];
      o += wsel[wave][h][r] * qkv[((size_t)(b * NV + j)) * 192 + 128 + h * DH + d];
    }
    obuf[wave][lane] = o;
  }
  __syncthreads();

  {
    float acc = bp[lane];
#pragma unroll 4
    for (int cc = 0; cc < CH; ++cc)
      acc = fmaf(obuf[wave][cc], wp[cc * CH + lane], acc);
    float a = mcan[row] ? acc : 0.0f;
    xres[(size_t)row * CH + lane] = 0.5f * a + xcan[(size_t)row * CH + lane];
  }
}

// ---------------- K4: LN2 + MLP + residual — MFMA version (R13) ----------------
#define XNS 72
#define GS  264
__global__ __launch_bounds__(256) void k_mlp(
    const float* __restrict__ xres, const float* __restrict__ pcan,
    const unsigned short* __restrict__ w1p,
    const unsigned short* __restrict__ w2p,
    const int* __restrict__ flags, void* __restrict__ out)
{
  __shared__ unsigned short xnb[16 * XNS];
  __shared__ unsigned short gb[16 * GS];
  const int tid = threadIdx.x;
  const int wave = tid >> 6, lane = tid & 63;
  const int row0 = blockIdx.x * 16;

  {
    const float gg = pcan[P_LN2G + lane], bb2 = pcan[P_LN2B + lane];
#pragma unroll
    for (int r = 0; r < 4; ++r) {
      int m = wave * 4 + r;
      float v = xres[(size_t)(row0 + m) * CH + lane];
      float mn = wave_sum_f32(v) * (1.0f / 64.0f);
      float d = v - mn;
      float var = wave_sum_f32(d * d) * (1.0f / 64.0f);
      float rs = 1.0f / sqrtf(var + 1e-5f);
      xnb[m * XNS + lane] =
          __bfloat16_as_ushort(__float2bfloat16(d * rs * gg + bb2));
    }
  }
  __syncthreads();

  const int q = lane >> 4, c = lane & 15;
  short8 a0 = *(const short8*)&xnb[c * XNS + q * 8];
  short8 a1 = *(const short8*)&xnb[c * XNS + 32 + q * 8];

  // ---- fc1 ----
  float4a acc[4];
#pragma unroll
  for (int t = 0; t < 4; ++t) {
    int nt = wave * 4 + t;
    short8 b0 = *(const short8*)&w1p[(size_t)((nt * 2 + 0) * 64 + lane) * 8];
    short8 b1 = *(const short8*)&w1p[(size_t)((nt * 2 + 1) * 64 + lane) * 8];
    float4a z = {0.f, 0.f, 0.f, 0.f};
    z = __builtin_amdgcn_mfma_f32_16x16x32_bf16(a0, b0, z, 0, 0, 0);
    z = __builtin_amdgcn_mfma_f32_16x16x32_bf16(a1, b1, z, 0, 0, 0);
    acc[t] = z;
  }
#pragma unroll
  for (int t = 0; t < 4; ++t) {
    int n = (wave * 4 + t) * 16 + c;
    float bo = pcan[P_B1 + n];
#pragma unroll
    for (int r = 0; r < 4; ++r) {
      float h = acc[t][r] + bo;
      float u = 0.7978845608028654f * (h + 0.044715f * h * h * h);
      float gv = 0.5f * h * (1.0f + tanh_fast(u));
      gb[(q * 4 + r) * GS + n] = __bfloat16_as_ushort(__float2bfloat16(gv));
    }
  }
  __syncthreads();

  // ---- fc2 ----
  float4a o = {0.f, 0.f, 0.f, 0.f};
#pragma unroll
  for (int kh = 0; kh < 8; ++kh) {
    short8 ag = *(const short8*)&gb[c * GS + kh * 32 + q * 8];
    short8 bg = *(const short8*)&w2p[(size_t)((wave * 8 + kh) * 64 + lane) * 8];
    o = __builtin_amdgcn_mfma_f32_16x16x32_bf16(ag, bg, o, 0, 0, 0);
  }
  {
    int n = wave * 16 + c;
    float b2v = pcan[P_B2 + n];
    const int isbf = flags[0];
#pragma unroll
    for (int r = 0; r < 4; ++r) {
      int m = q * 4 + r;
      size_t idx = (size_t)(row0 + m) * CH + n;
      float val = 0.5f * (o[r] + b2v) + xres[idx];
      if (isbf) ((bf16*)out)[idx] = __float2bfloat16(val);
      else      ((float*)out)[idx] = val;
    }
  }
}

extern "C" void kernel_launch(void* const* d_in, const int* in_sizes, int n_in,
                              void* d_out, int out_size, void* d_ws, size_t ws_size,
                              hipStream_t stream)
{
  char* ws = (char*)d_ws;
  float* qkv   = (float*)(ws);
  float* xres  = (float*)(ws + 12582912);
  float* xcan  = (float*)(ws + 16777216);
  float* ccan  = (float*)(ws + 20971520);
  float* pcan  = (float*)(ws + 21168128);
  int*   mcan  = (int*)  (ws + 21368064);
  int*   nbr   = (int*)  (ws + 21433600);
  int*   flags = (int*)  (ws + 22088960);
  unsigned short* w1p = (unsigned short*)(ws + 22089728);   // 32 KB
  unsigned short* w2p = (unsigned short*)(ws + 22122496);   // 32 KB
  unsigned short* wqp = (unsigned short*)(ws + 22155264);   // 24 KB

  const int total = N_ING + N_PACK;
  k_prep<<<(total + 255) / 256, 256, 0, stream>>>(
      d_in[0], d_in[1], d_in[2], d_in[3], d_in[4], d_in[5], d_in[6],
      d_in[7], d_in[8], d_in[9], d_in[10], d_in[11], d_in[12], d_in[13], d_in[14],
      xcan, ccan, pcan, mcan, w1p, w2p, wqp, flags);
  k_ln_qkv<<<BN / 16, 256, 0, stream>>>(xcan, pcan, wqp, qkv);
  k_knn<<<BN / KROWS, 256, 0, stream>>>(ccan, mcan, nbr);
  k_attn<<<BN / AROWS, 256, 0, stream>>>(qkv, nbr, mcan, xcan, pcan, xres);
  k_mlp<<<BN / 16, 256, 0, stream>>>(xres, pcan, w1p, w2p, flags, d_out);
}